// Round 8
// baseline (134.824 us; speedup 1.0000x reference)
//
#include <hip/hip_runtime.h>

#define HH 128
#define WW 128
#define CC 64
#define OO 64
#define KK 9
#define PLANE (HH * WW)

#define BAND 8
#define BAND_B (BAND * 128 * 64)   // 65536

typedef _Float16 half8v __attribute__((ext_vector_type(8)));
typedef _Float16 half2v __attribute__((ext_vector_type(2)));
typedef float floatx4 __attribute__((ext_vector_type(4)));

__device__ __forceinline__ unsigned pkpair(float a, float b) {
    return __builtin_bit_cast(unsigned, __builtin_amdgcn_cvt_pkrtz(a, b));
}
__device__ __forceinline__ half2v h2(unsigned u) {
    return __builtin_bit_cast(half2v, u);
}

// ---------- combined prep: blocks [0,2048) NCHW->split-half NHWC f16; rest weight ----------
__global__ __launch_bounds__(256)
void prep_kernel(const float* __restrict__ in, const float* __restrict__ wsrc,
                 unsigned short* __restrict__ outT, _Float16* __restrict__ wt4) {
    __shared__ unsigned tile[64 * 36];
    int blk = blockIdx.x;
    int t = threadIdx.x;
    if (blk < 2048) {
        int b = blk & 7;                     // XCD swizzle
        int rest = blk >> 3;
        int y = rest >> 1;
        int xh = rest & 1;
        int p = t & 63;
        int cg = t >> 6;                     // 0..3
        const float* src = in + (size_t)(b * 64) * PLANE + y * WW + xh * 64 + p;
#pragma unroll
        for (int i = 0; i < 8; ++i) {
            int c0 = cg * 16 + 2 * i;
            float v0 = src[(size_t)c0 * PLANE];
            float v1 = src[(size_t)(c0 + 1) * PLANE];
            unsigned lo = __builtin_bit_cast(unsigned short, (_Float16)v0);
            unsigned hi = __builtin_bit_cast(unsigned short, (_Float16)v1);
            tile[p * 36 + (c0 >> 1)] = lo | (hi << 16);
        }
        __syncthreads();
        int p2 = t >> 2;                     // px 0..63
        int q = t & 3;                       // ch-16 group
        const unsigned* s = &tile[p2 * 36 + q * 8];
        uint4 w0 = *(const uint4*)s;
        uint4 w1 = *(const uint4*)(s + 4);
        int half = q >> 1;
        char* dst = (char*)outT + ((size_t)(b * 2 + half) << 20)
                  + (size_t)(y * 128 + xh * 64 + p2) * 64 + (q & 1) * 32;
        *(uint4*)dst = w0;
        *(uint4*)(dst + 16) = w1;
    } else {
        int idx = (blk - 2048) * 256 + t;
        if (idx < 2 * KK * 4 * 64 * 8) {
            int j = idx & 7;
            int lane = (idx >> 3) & 63;
            int nt = (idx >> 9) & 3;
            int pk = idx >> 11;              // pass*9 + k
            int k = pk % 9;
            int pass = pk / 9;
            int o = nt * 16 + (lane & 15);
            int c = pass * 32 + (lane >> 4) * 8 + j;
            wt4[idx] = (_Float16)wsrc[(o * 64 + c) * 9 + k];
        }
    }
}

// ---------- main: 2 blocks/CU, swizzled 8-row band, pipelined desc, global fallback ----------
__global__ __launch_bounds__(256, 2)
void deform_mfma_kernel(const unsigned short* __restrict__ dataT,
                        const float* __restrict__ offset,
                        const _Float16* __restrict__ wt4,
                        float* __restrict__ out) {
    __shared__ __align__(16) char SB[BAND_B];     // 65536: swizzled band
    __shared__ unsigned sOff[KK][128];            // 4608:  packed corner info
    __shared__ uint2 sWt[KK][128];                // 9216:  packed f16 weights

    const int t = threadIdx.x;
    const int lane = t & 63;
    const int w = t >> 6;                // wave 0..3
    const int quad = lane >> 4;
    const int l15 = lane & 15;
    const int raw = blockIdx.x;
    const int b = raw & 7;               // XCD-aligned batch
    const int ho = raw >> 3;
    const int mbase = w * 32;
    const int bs = min(max(ho - 3, 0), HH - BAND);

    // ---- wave-local descriptors: 32 px x 9 k per wave, no barrier ----
#pragma unroll
    for (int i = 0; i < 5; ++i) {
        int idx = i * 64 + lane;
        if (idx < 288) {
            int k = idx >> 5;
            int px = mbase + (idx & 31);
            const float* offp = offset + ((size_t)(b * 18) + 2 * k) * PLANE + ho * WW + px;
            float oy = offp[0];
            float ox = offp[PLANE];
            float py = (float)(ho - 1 + k / 3) + oy;
            float pxx = (float)(px - 1 + k % 3) + ox;
            float y0f = floorf(py);
            float x0f = floorf(pxx);
            float fy = py - y0f;
            float fx = pxx - x0f;
            int y0 = (int)y0f, x0 = (int)x0f;
            int y1 = y0 + 1, x1 = x0 + 1;
            float wy0 = (1.f - fy) * ((y0 >= 0 && y0 < HH) ? 1.f : 0.f);
            float wy1 = fy * ((y1 >= 0 && y1 < HH) ? 1.f : 0.f);
            float wx0 = (1.f - fx) * ((x0 >= 0 && x0 < WW) ? 1.f : 0.f);
            float wx1 = fx * ((x1 >= 0 && x1 < WW) ? 1.f : 0.f);
            int yc0 = min(max(y0, 0), HH - 1);
            int yc1 = min(max(y1, 0), HH - 1);
            int x_lo = min(max(x0, 0), WW - 2);
            float wA = ((x0 == x_lo) ? wx0 : 0.f) + ((x1 == x_lo) ? wx1 : 0.f);
            float wB = ((x0 == x_lo + 1) ? wx0 : 0.f) + ((x1 == x_lo + 1) ? wx1 : 0.f);

            unsigned v0, v1, d;
            {
                int r = yc0 - bs;
                if (wy0 == 0.f) { v0 = (unsigned)x_lo; d = 0; }
                else if ((unsigned)r < BAND) { v0 = (unsigned)(r * 128 + x_lo); d = 0; }
                else { v0 = (unsigned)(yc0 * 128 + x_lo); d = 0x4000u; }
            }
            {
                int r = yc1 - bs;
                if (wy1 == 0.f) v1 = (unsigned)x_lo;
                else if ((unsigned)r < BAND) v1 = (unsigned)(r * 128 + x_lo);
                else { v1 = (unsigned)(yc1 * 128 + x_lo); d |= 0x20000000u; }
            }
            sOff[k][px] = d | v0 | (v1 << 15);
            sWt[k][px] = make_uint2(pkpair(wy0 * wA, wy0 * wB),
                                    pkpair(wy1 * wA, wy1 * wB));
        }
    }

    floatx4 acc[2][4];
#pragma unroll
    for (int mt = 0; mt < 2; ++mt)
#pragma unroll
        for (int nt = 0; nt < 4; ++nt)
            acc[mt][nt] = (floatx4){0.f, 0.f, 0.f, 0.f};

    const int p0 = mbase + l15;
    const int p1 = mbase + 16 + l15;

    for (int pass = 0; pass < 2; ++pass) {
        if (pass) __syncthreads();           // gather of pass 0 done before re-stage
        const char* gh = (const char*)dataT + ((size_t)(b * 2 + pass) << 20);
        // ---- stage swizzled band: 4096 16B units ----
        {
            const char* gsrc = gh + (unsigned)(bs * 8192);
#pragma unroll
            for (int i = 0; i < 16; ++i) {
                int u = i * 256 + t;
                uint4 v = *(const uint4*)(gsrc + (size_t)u * 16);
                int pxl = u >> 2, q = u & 3;
                *(uint4*)(SB + pxl * 64 + (((q + pxl) & 3) << 4)) = v;
            }
        }
        __syncthreads();

        // per-(k,mt) compute with descriptor in registers
        auto compute = [&](unsigned d, uint2 wp, floatx4* accrow) {
            unsigned v0 = d & 0x3fffu;
            unsigned v1 = (d >> 15) & 0x3fffu;
            unsigned rot00 = ((quad + v0) & 3u) << 4;
            unsigned rot01 = ((quad + v0 + 1) & 3u) << 4;
            unsigned rot10 = ((quad + v1) & 3u) << 4;
            unsigned rot11 = ((quad + v1 + 1) & 3u) << 4;
            uint4 v00 = *(const uint4*)(SB + ((v0 & 1023u) << 6) + rot00);
            uint4 v01 = *(const uint4*)(SB + ((v0 & 1023u) << 6) + 64 + rot01);
            uint4 v10 = *(const uint4*)(SB + ((v1 & 1023u) << 6) + rot10);
            uint4 v11 = *(const uint4*)(SB + ((v1 & 1023u) << 6) + 64 + rot11);
            if (d & 0x4000u) {               // rare out-of-band corner 0
                const char* g = gh + ((size_t)v0 << 6) + (quad << 4);
                v00 = *(const uint4*)g;
                v01 = *(const uint4*)(g + 64);
            }
            if (d & 0x20000000u) {           // rare out-of-band corner 1
                const char* g = gh + ((size_t)v1 << 6) + (quad << 4);
                v10 = *(const uint4*)g;
                v11 = *(const uint4*)(g + 64);
            }
            half2v wv0 = h2(wp.x), wv1 = h2(wp.y);
            half2v h00 = __builtin_shufflevector(wv0, wv0, 0, 0);
            half2v h01 = __builtin_shufflevector(wv0, wv0, 1, 1);
            half2v h10 = __builtin_shufflevector(wv1, wv1, 0, 0);
            half2v h11 = __builtin_shufflevector(wv1, wv1, 1, 1);
            half2v s0 = h2(v00.x) * h00 + h2(v01.x) * h01 + h2(v10.x) * h10 + h2(v11.x) * h11;
            half2v s1 = h2(v00.y) * h00 + h2(v01.y) * h01 + h2(v10.y) * h10 + h2(v11.y) * h11;
            half2v s2 = h2(v00.z) * h00 + h2(v01.z) * h01 + h2(v10.z) * h10 + h2(v11.z) * h11;
            half2v s3 = h2(v00.w) * h00 + h2(v01.w) * h01 + h2(v10.w) * h10 + h2(v11.w) * h11;
            uint4 sv = make_uint4(__builtin_bit_cast(unsigned, s0),
                                  __builtin_bit_cast(unsigned, s1),
                                  __builtin_bit_cast(unsigned, s2),
                                  __builtin_bit_cast(unsigned, s3));
            half8v afrag = __builtin_bit_cast(half8v, sv);   // A[m=l15][c=quad*8+j]
#pragma unroll
            for (int nt = 0; nt < 4; ++nt)
                accrow[nt] = __builtin_amdgcn_mfma_f32_16x16x32_f16(
                    afrag, __builtin_bit_cast(half8v, ((const uint4*)nullptr == nullptr, accrow[nt])), accrow[nt], 0, 0, 0);
        };
        (void)compute;  // replaced below with explicit loop (needs bfr)

        // ---- k-loop with one-ahead prefetch of desc + B-frags ----
        unsigned dc0 = sOff[0][p0], dc1 = sOff[0][p1];
        uint2 wc0 = sWt[0][p0], wc1 = sWt[0][p1];
        uint4 bc[4];
        {
            const uint4* wk = (const uint4*)wt4 + (size_t)(pass * 9 * 4) * 64 + lane;
#pragma unroll
            for (int nt = 0; nt < 4; ++nt) bc[nt] = wk[nt * 64];
        }
        for (int k = 0; k < KK; ++k) {
            unsigned dn0 = 0, dn1 = 0;
            uint2 wn0 = make_uint2(0, 0), wn1 = make_uint2(0, 0);
            uint4 bn[4];
            if (k < 8) {
                dn0 = sOff[k + 1][p0];
                dn1 = sOff[k + 1][p1];
                wn0 = sWt[k + 1][p0];
                wn1 = sWt[k + 1][p1];
                const uint4* wk = (const uint4*)wt4 + (size_t)((pass * 9 + k + 1) * 4) * 64 + lane;
#pragma unroll
                for (int nt = 0; nt < 4; ++nt) bn[nt] = wk[nt * 64];
            }
#pragma unroll
            for (int mt = 0; mt < 2; ++mt) {
                unsigned d = mt ? dc1 : dc0;
                uint2 wp = mt ? wc1 : wc0;
                unsigned v0 = d & 0x3fffu;
                unsigned v1 = (d >> 15) & 0x3fffu;
                unsigned rot00 = ((quad + v0) & 3u) << 4;
                unsigned rot01 = ((quad + v0 + 1) & 3u) << 4;
                unsigned rot10 = ((quad + v1) & 3u) << 4;
                unsigned rot11 = ((quad + v1 + 1) & 3u) << 4;
                uint4 v00 = *(const uint4*)(SB + ((v0 & 1023u) << 6) + rot00);
                uint4 v01 = *(const uint4*)(SB + ((v0 & 1023u) << 6) + 64 + rot01);
                uint4 v10 = *(const uint4*)(SB + ((v1 & 1023u) << 6) + rot10);
                uint4 v11 = *(const uint4*)(SB + ((v1 & 1023u) << 6) + 64 + rot11);
                if (d & 0x4000u) {
                    const char* g = gh + ((size_t)v0 << 6) + (quad << 4);
                    v00 = *(const uint4*)g;
                    v01 = *(const uint4*)(g + 64);
                }
                if (d & 0x20000000u) {
                    const char* g = gh + ((size_t)v1 << 6) + (quad << 4);
                    v10 = *(const uint4*)g;
                    v11 = *(const uint4*)(g + 64);
                }
                half2v wv0 = h2(wp.x), wv1 = h2(wp.y);
                half2v h00 = __builtin_shufflevector(wv0, wv0, 0, 0);
                half2v h01 = __builtin_shufflevector(wv0, wv0, 1, 1);
                half2v h10 = __builtin_shufflevector(wv1, wv1, 0, 0);
                half2v h11 = __builtin_shufflevector(wv1, wv1, 1, 1);
                half2v s0 = h2(v00.x) * h00 + h2(v01.x) * h01 + h2(v10.x) * h10 + h2(v11.x) * h11;
                half2v s1 = h2(v00.y) * h00 + h2(v01.y) * h01 + h2(v10.y) * h10 + h2(v11.y) * h11;
                half2v s2 = h2(v00.z) * h00 + h2(v01.z) * h01 + h2(v10.z) * h10 + h2(v11.z) * h11;
                half2v s3 = h2(v00.w) * h00 + h2(v01.w) * h01 + h2(v10.w) * h10 + h2(v11.w) * h11;
                uint4 sv = make_uint4(__builtin_bit_cast(unsigned, s0),
                                      __builtin_bit_cast(unsigned, s1),
                                      __builtin_bit_cast(unsigned, s2),
                                      __builtin_bit_cast(unsigned, s3));
                half8v afrag = __builtin_bit_cast(half8v, sv);   // A[m=l15][c=quad*8+j]
#pragma unroll
                for (int nt = 0; nt < 4; ++nt)
                    acc[mt][nt] = __builtin_amdgcn_mfma_f32_16x16x32_f16(
                        afrag, __builtin_bit_cast(half8v, bc[nt]), acc[mt][nt], 0, 0, 0);
            }
            if (k < 8) {
                dc0 = dn0; dc1 = dn1; wc0 = wn0; wc1 = wn1;
#pragma unroll
                for (int nt = 0; nt < 4; ++nt) bc[nt] = bn[nt];
            }
        }
    }

    // ---- epilogue: D col=lane&15 (=o), row=quad*4+reg (=pixel) ----
#pragma unroll
    for (int mt = 0; mt < 2; ++mt)
#pragma unroll
        for (int nt = 0; nt < 4; ++nt) {
            int o = nt * 16 + l15;
            int px = mbase + mt * 16 + quad * 4;
            float* dst = out + (size_t)(b * 64 + o) * PLANE + ho * 128 + px;
            *(floatx4*)dst = acc[mt][nt];
        }
}

// ================= fallback (round-1 scalar path) =================
__global__ void transpose_weight_kernel(const float* __restrict__ w,
                                        float* __restrict__ wt) {
    int i = blockIdx.x * 256 + threadIdx.x;
    if (i < CC * KK * OO) {
        int o = i & 63;
        int ck = i >> 6;
        wt[i] = w[o * (CC * KK) + ck];
    }
}

__global__ __launch_bounds__(256)
void deform_conv_kernel(const float* __restrict__ data,
                        const float* __restrict__ offset,
                        const float* __restrict__ wt,
                        float* __restrict__ out) {
    const int tid = threadIdx.x;
    const int wo = tid & 127;
    int ohalf = tid >> 7;
    ohalf = __builtin_amdgcn_readfirstlane(ohalf);
    const int row = blockIdx.x;
    const int b = row >> 7;
    const int ho = row & 127;
    int abyte[KK][4];
    float wgt[KK][4];
    const float* offBase = offset + ((size_t)b * 18) * PLANE + ho * WW + wo;
#pragma unroll
    for (int k = 0; k < KK; ++k) {
        float oy = offBase[(2 * k) * PLANE];
        float ox = offBase[(2 * k + 1) * PLANE];
        float py = oy + (float)(ho - 1 + k / 3);
        float px = ox + (float)(wo - 1 + k % 3);
        float y0f = floorf(py);
        float x0f = floorf(px);
        float wy1 = py - y0f, wx1 = px - x0f;
        float wy0 = 1.f - wy1, wx0 = 1.f - wx1;
        int y0 = (int)y0f, x0 = (int)x0f;
        int y1 = y0 + 1, x1 = x0 + 1;
        float my0 = (y0 >= 0 && y0 < HH) ? 1.f : 0.f;
        float my1 = (y1 >= 0 && y1 < HH) ? 1.f : 0.f;
        float mx0 = (x0 >= 0 && x0 < WW) ? 1.f : 0.f;
        float mx1 = (x1 >= 0 && x1 < WW) ? 1.f : 0.f;
        int yc0 = min(max(y0, 0), HH - 1);
        int yc1 = min(max(y1, 0), HH - 1);
        int xc0 = min(max(x0, 0), WW - 1);
        int xc1 = min(max(x1, 0), WW - 1);
        abyte[k][0] = (yc0 * WW + xc0) * 4;
        abyte[k][1] = (yc0 * WW + xc1) * 4;
        abyte[k][2] = (yc1 * WW + xc0) * 4;
        abyte[k][3] = (yc1 * WW + xc1) * 4;
        wgt[k][0] = wy0 * wx0 * my0 * mx0;
        wgt[k][1] = wy0 * wx1 * my0 * mx1;
        wgt[k][2] = wy1 * wx0 * my1 * mx0;
        wgt[k][3] = wy1 * wx1 * my1 * mx1;
    }
    float acc[32];
#pragma unroll
    for (int j = 0; j < 32; ++j) acc[j] = 0.f;
    const float* planeBase = data + (size_t)b * CC * PLANE;
    const float4* wt4base = (const float4*)wt + ohalf * 8;
    for (int c = 0; c < CC; ++c) {
        const char* pc = (const char*)(planeBase + c * PLANE);
#pragma unroll
        for (int k = 0; k < KK; ++k) {
            float v00 = *(const float*)(pc + abyte[k][0]);
            float v01 = *(const float*)(pc + abyte[k][1]);
            float v10 = *(const float*)(pc + abyte[k][2]);
            float v11 = *(const float*)(pc + abyte[k][3]);
            float s = wgt[k][0] * v00 + wgt[k][1] * v01 +
                      wgt[k][2] * v10 + wgt[k][3] * v11;
            const float4* wp = wt4base + (c * KK + k) * 16;
#pragma unroll
            for (int j = 0; j < 8; ++j) {
                float4 wv = wp[j];
                acc[4 * j + 0] += s * wv.x;
                acc[4 * j + 1] += s * wv.y;
                acc[4 * j + 2] += s * wv.z;
                acc[4 * j + 3] += s * wv.w;
            }
        }
    }
    float* outp = out + ((size_t)b * OO + ohalf * 32) * PLANE + ho * WW + wo;
#pragma unroll
    for (int j = 0; j < 32; ++j) outp[j * PLANE] = acc[j];
}

extern "C" void kernel_launch(void* const* d_in, const int* in_sizes, int n_in,
                              void* d_out, int out_size, void* d_ws, size_t ws_size,
                              hipStream_t stream) {
    const float* data = (const float*)d_in[0];    // (8,64,128,128) f32
    const float* offset = (const float*)d_in[1];  // (8,18,128,128) f32
    const float* weight = (const float*)d_in[2];  // (64,64,3,3) f32
    float* out = (float*)d_out;                   // (8,64,128,128) f32

    const size_t DATA_T_BYTES = (size_t)8 * 2 * 128 * 128 * 64;   // 16,777,216 (split-half f16)
    const size_t WT4_BYTES = (size_t)2 * KK * 4 * 64 * 8 * 2;     // 73,728

    if (ws_size >= DATA_T_BYTES + WT4_BYTES) {
        unsigned short* dataT = (unsigned short*)d_ws;
        _Float16* wt4 = (_Float16*)((char*)d_ws + DATA_T_BYTES);
        prep_kernel<<<2048 + 144, 256, 0, stream>>>(data, weight, dataT, wt4);
        deform_mfma_kernel<<<8 * HH, 256, 0, stream>>>(dataT, offset, wt4, out);
    } else {
        float* wt = (float*)d_ws;
        int nw = CC * KK * OO;
        transpose_weight_kernel<<<(nw + 255) / 256, 256, 0, stream>>>(weight, wt);
        deform_conv_kernel<<<8 * HH, 256, 0, stream>>>(data, offset, wt, out);
    }
}